// Round 7
// baseline (497.130 us; speedup 1.0000x reference)
//
#include <hip/hip_runtime.h>
#include <stdint.h>

typedef unsigned short ushort_t;

#define B8  8
#define D6  6
#define NC  48
#define HH  256
#define WW  256
#define HWp 65536
#define H2  128
#define HW2 16384

__device__ __constant__ int c_T0[8] = {0,1,1,1,0,-1,-1,-1};
__device__ __constant__ int c_T1[8] = {1,1,0,-1,-1,-1,0,1};

__device__ inline float bf2f(ushort_t u){ union{unsigned int i; float f;} w; w.i = ((unsigned int)u)<<16; return w.f; }
__device__ inline ushort_t f2bf(float f){ union{float f; unsigned int i;} w; w.f=f; unsigned int xx=w.i;
  return (ushort_t)((xx + 0x7fffu + ((xx>>16)&1u)) >> 16); }
__device__ inline float tanhf_(float x){ float e=__expf(2.f*x); return 1.f - 2.f/(e+1.f); }
__device__ inline float sigm_(float x){ return 1.f/(1.f+__expf(-x)); }
__device__ inline float ldg_(const void* p, size_t i, int isbf){
  return isbf ? bf2f(((const ushort_t*)p)[i]) : ((const float*)p)[i];
}

typedef short short8 __attribute__((ext_vector_type(8)));
typedef float f4 __attribute__((ext_vector_type(4)));
typedef ushort_t us4 __attribute__((ext_vector_type(4)));
typedef ushort_t us8 __attribute__((ext_vector_type(8)));
union AB { short8 s; us4 h[2]; us8 u; };

// ---------------- dtype detection ----------------
__global__ __launch_bounds__(256) void k_detect(const ushort_t* x, float* flag){
  int t=threadIdx.x; int cnt=0;
  for(int i=t;i<4096;i+=256){
    ushort_t u=x[2*i];
    int e=(u>>7)&0xff;
    if(e>=100 && e<=150) cnt++;
  }
  for(int o=32;o;o>>=1) cnt+=__shfl_down(cnt,o,64);
  __shared__ int sh4[4];
  if((t&63)==0) sh4[t>>6]=cnt;
  __syncthreads();
  if(t==0){ int tot=sh4[0]+sh4[1]+sh4[2]+sh4[3]; flag[0] = (tot>=2048)?1.f:0.f; }
}

// ---------------- weight conversion to fp32 ----------------
struct WC { const ushort_t* src[10]; int off[10]; int n[10]; };

__global__ __launch_bounds__(256) void k_wcvt(WC wc, float* dst, const float* dfl){
  int isbf = dfl[0]>0.5f;
  int t = blockIdx.y; int n = wc.n[t]; const ushort_t* s = wc.src[t]; float* d = dst + wc.off[t];
  for(int i = blockIdx.x*256 + threadIdx.x; i < n; i += gridDim.x*256)
    d[i] = isbf ? bf2f(s[i]) : ((const float*)s)[i];
}

// ---------------- MFMA weight prep ----------------
__global__ __launch_bounds__(256) void k_wprep(const float* w2src, const float* w1src,
                                               ushort_t* wb2, ushort_t* wb1){
  int t = blockIdx.x*256+threadIdx.x;
  if(t<3456){
    int lane=t&63; int rest=t>>6;
    int ks=rest&1; int g=rest>>1; int tap=g%9; int nt=g/9;
    int oc=nt*16+(lane&15); int icb=ks*32+((lane>>4)*8);
    #pragma unroll
    for(int j=0;j<8;j++){
      int ic=icb+j;
      float v = (ic<48) ? w2src[(oc*48+ic)*9+tap] : 0.f;
      wb2[(size_t)t*8+j]=f2bf(v);
    }
  } else if(t<5184){
    int tt=t-3456; int lane=tt&63; int g=tt>>6; int tap=g%9; int nt=g/9;
    int oc=nt*16+(lane&15); int icb=(lane>>4)*8;
    #pragma unroll
    for(int j=0;j<8;j++){
      int ic=icb+j;
      float v = (ic<10) ? w1src[(oc*10+ic)*9+tap] : 0.f;
      wb1[(size_t)tt*8+j]=f2bf(v);
    }
  }
}

// ---------------- 6-channel moment reduction ----------------
__global__ __launch_bounds__(256) void k_mom(const void* src, const float* dfl, int isbfc,
                                             int sh, int npix, float* out){
  int isbf = dfl ? (dfl[0]>0.5f) : isbfc;
  float vals[27];
  #pragma unroll
  for(int i=0;i<27;i++) vals[i]=0.f;
  int stride = gridDim.x*256;
  int msk = (1<<sh)-1;
  for(int p = blockIdx.x*256+threadIdx.x; p < npix; p += stride){
    int b = p >> sh; int hw = p & msk;
    float v[6];
    #pragma unroll
    for(int d=0; d<6; d++){
      size_t idx = (((size_t)(b*6+d))<<sh) + hw;
      v[d] = ldg_(src, idx, isbf);
    }
    int q=6;
    #pragma unroll
    for(int d=0;d<6;d++){
      vals[d]+=v[d];
      #pragma unroll
      for(int e=d;e<6;e++){ vals[q] += v[d]*v[e]; q++; }
    }
  }
  __shared__ float red[4][27];
  int wid=threadIdx.x>>6, lane=threadIdx.x&63;
  #pragma unroll
  for(int i=0;i<27;i++){
    float v=vals[i];
    for(int o=32;o;o>>=1) v+=__shfl_down(v,o,64);
    if(lane==0) red[wid][i]=v;
  }
  __syncthreads();
  if(threadIdx.x<27)
    atomicAdd(&out[threadIdx.x],
      red[0][threadIdx.x]+red[1][threadIdx.x]+red[2][threadIdx.x]+red[3][threadIdx.x]);
}

__global__ __launch_bounds__(64) void k_msb(const float* mom, const float* W1,
      const void* g, const void* b, const float* dfl, float invN, float* scale, float* bias){
  int c = threadIdx.x; if(c>=NC) return;
  int isbf = dfl[0]>0.5f;
  const int st[6]={0,6,11,15,18,20};
  float wr[6];
  #pragma unroll
  for(int d=0;d<6;d++) wr[d]=W1[c*6+d];
  float mean=0.f;
  #pragma unroll
  for(int d=0;d<6;d++) mean += wr[d]*mom[d];
  mean *= invN;
  float e2=0.f;
  #pragma unroll
  for(int d=0;d<6;d++){
    #pragma unroll
    for(int e=d;e<6;e++){
      float mm = mom[6 + st[d] + (e-d)];
      e2 += wr[d]*wr[e]*((e==d)?1.f:2.f)*mm;
    }
  }
  e2 *= invN;
  float var = e2 - mean*mean;
  float sc = ldg_(g,c,isbf) * rsqrtf(var + 1e-5f);
  scale[c]=sc; bias[c]= ldg_(b,c,isbf) - sc*mean;
}

// ---------------- compenv ----------------
__global__ __launch_bounds__(256) void k_env(const void* x, const float* dfl,
      const float* w1, const float* w2, const float* sc, const float* bi, float* e){
  int isbf = dfl[0]>0.5f;
  int p = blockIdx.x*256+threadIdx.x;
  int b = p >> 16; int hw = p & 65535;
  float v[6];
  #pragma unroll
  for(int d=0; d<6; d++) v[d]=ldg_(x,(size_t)(b*6+d)*HWp + hw, isbf);
  float acc=0.f;
  for(int c=0;c<NC;c++){
    float y=0.f;
    #pragma unroll
    for(int d=0;d<6;d++) y += w1[c*6+d]*v[d];
    acc += w2[c]*tanhf_(sc[c]*y + bi[c]);
  }
  e[(size_t)b*HWp + hw]=acc;
}

// ---------------- h1 (MFMA) -> channels-last bf16 [8][258][258][48] ----------------
__global__ __launch_bounds__(256) void k_h1m(const void* x, const float* dfl, const float* e,
      const ushort_t* wb1, ushort_t* h1cl){
  __shared__ __attribute__((aligned(16))) ushort_t tile[324*24];  // [pix 18x18][icdim 24]
  int isbf = dfl[0]>0.5f;
  int b = blockIdx.y;
  int ti = blockIdx.x/17, tj = blockIdx.x%17;
  int i0 = ti*16, j0 = tj*16;
  {
    us8 z;
    #pragma unroll
    for(int j=0;j<8;j++) z[j]=0;
    us8* tp=(us8*)tile;
    for(int idx=threadIdx.x; idx<972; idx+=256) tp[idx]=z;
  }
  __syncthreads();
  for(int idx=threadIdx.x; idx<3240; idx+=256){
    int pix = idx/10, ic = idx-pix*10;
    int r = pix/18, c = pix-r*18;
    int gy = i0-2+r, gx = j0-2+c;
    float v = 0.f;
    if(gy>=0 && gy<HH && gx>=0 && gx<WW){
      if(ic<2) v = ldg_(x, ((size_t)(b*6+ic)*HH + gy)*WW + gx, isbf);
      else { int k=ic-2;
        int yy=(gy + c_T1[k]) & 255; int xx=(gx - c_T0[k]) & 255;
        v = e[((size_t)b*HH + yy)*WW + xx]; }
    }
    tile[pix*24+ic]=f2bf(v);
  }
  __syncthreads();
  int lane = threadIdx.x&63, w = threadIdx.x>>6;
  int n = lane&15, quad = lane>>4;
  int qoff = (quad<2) ? quad*8 : 16;   // quads 2,3 -> zero slots (B=0 there)
  f4 acc[4][3];
  #pragma unroll
  for(int a=0;a<4;a++)
    #pragma unroll
    for(int c=0;c<3;c++) acc[a][c]=(f4){0.f,0.f,0.f,0.f};
  for(int tap=0; tap<9; tap++){
    int ki=tap/3, kj=tap%3;
    AB Bf[3];
    #pragma unroll
    for(int nt=0;nt<3;nt++) Bf[nt].u = *(const us8*)&wb1[((size_t)((nt*9+tap)*64+lane))*8];
    #pragma unroll
    for(int yy=0; yy<4; yy++){
      int y = w*4 + yy;
      AB a; a.u = *(const us8*)&tile[((y+ki)*18 + n + kj)*24 + qoff];
      #pragma unroll
      for(int nt=0;nt<3;nt++)
        acc[yy][nt] = __builtin_amdgcn_mfma_f32_16x16x32_bf16(a.s, Bf[nt].s, acc[yy][nt], 0,0,0);
    }
  }
  #pragma unroll
  for(int yy=0;yy<4;yy++){
    int Y = i0 + w*4 + yy;
    if(Y>=258) continue;
    #pragma unroll
    for(int nt=0;nt<3;nt++){
      int oc = nt*16 + n;
      #pragma unroll
      for(int r=0;r<4;r++){
        int X = j0 + quad*4 + r;
        if(X<258)
          h1cl[(((size_t)b*258 + Y)*258 + X)*48 + oc] = f2bf(tanhf_(acc[yy][nt][r]));
      }
    }
  }
}

// ---------------- h2 (MFMA) -> planar bf16 [8][48][256][256], fused BN stats ----------------
// A-fragments read DIRECTLY from channels-last h1cl (no LDS tile, no K-loop barriers).
// ks=1 quads 2/3 read past ch48 into the next pixel: finite garbage x B=0 = 0.
__global__ __launch_bounds__(256) void k_h2m(const ushort_t* h1cl, const ushort_t* wb2,
      ushort_t* h2h, float* stats){
  __shared__ float red[4][3][16][2];
  int b = blockIdx.y;
  int ti = blockIdx.x>>4, tj = blockIdx.x&15;
  int i0 = ti*16, j0 = tj*16;
  int lane = threadIdx.x&63, w = threadIdx.x>>6;
  int n = lane&15, quad = lane>>4;
  f4 acc[4][3];
  #pragma unroll
  for(int a=0;a<4;a++)
    #pragma unroll
    for(int c=0;c<3;c++) acc[a][c]=(f4){0.f,0.f,0.f,0.f};
  for(int tap=0; tap<9; tap++){
    int ki=tap/3, kj=tap%3;
    AB Bf[3][2];
    #pragma unroll
    for(int nt=0;nt<3;nt++)
      #pragma unroll
      for(int ks=0;ks<2;ks++)
        Bf[nt][ks].u = *(const us8*)&wb2[((size_t)(((nt*9+tap)*2+ks)*64+lane))*8];
    #pragma unroll
    for(int yy=0; yy<4; yy++){
      int Y = i0 + w*4 + yy;
      const ushort_t* ap = &h1cl[(((size_t)b*258 + Y+ki)*258 + (j0+n+kj))*48 + quad*8];
      AB a0, a1;
      a0.u = *(const us8*)ap;
      a1.u = *(const us8*)(ap+32);
      #pragma unroll
      for(int nt=0;nt<3;nt++){
        acc[yy][nt] = __builtin_amdgcn_mfma_f32_16x16x32_bf16(a0.s, Bf[nt][0].s, acc[yy][nt], 0,0,0);
        acc[yy][nt] = __builtin_amdgcn_mfma_f32_16x16x32_bf16(a1.s, Bf[nt][1].s, acc[yy][nt], 0,0,0);
      }
    }
  }
  float s[3]={0.f,0.f,0.f}, q[3]={0.f,0.f,0.f};
  #pragma unroll
  for(int yy=0;yy<4;yy++){
    int Y = i0 + w*4 + yy;
    #pragma unroll
    for(int nt=0;nt<3;nt++){
      int oc = nt*16 + n;
      size_t base = ((size_t)(b*NC+oc)*HH + Y)*WW + j0 + quad*4;
      us4 u;
      #pragma unroll
      for(int r=0;r<4;r++){
        float v=tanhf_(acc[yy][nt][r]);
        u[r]=f2bf(v);
        float vb=bf2f(u[r]);
        s[nt]+=vb; q[nt]+=vb*vb;
      }
      *(us4*)&h2h[base] = u;
    }
  }
  #pragma unroll
  for(int nt=0;nt<3;nt++){
    s[nt]+=__shfl_xor(s[nt],16,64); s[nt]+=__shfl_xor(s[nt],32,64);
    q[nt]+=__shfl_xor(q[nt],16,64); q[nt]+=__shfl_xor(q[nt],32,64);
  }
  if(quad==0){
    #pragma unroll
    for(int nt=0;nt<3;nt++){ red[w][nt][n][0]=s[nt]; red[w][nt][n][1]=q[nt]; }
  }
  __syncthreads();
  if(threadIdx.x<48){
    int oc=threadIdx.x; int nt=oc>>4, nn=oc&15;
    float S=red[0][nt][nn][0]+red[1][nt][nn][0]+red[2][nt][nn][0]+red[3][nt][nn][0];
    float Q=red[0][nt][nn][1]+red[1][nt][nn][1]+red[2][nt][nn][1]+red[3][nt][nn][1];
    atomicAdd(&stats[2*oc],S); atomicAdd(&stats[2*oc+1],Q);
  }
}

// ---------------- per-channel sum/sumsq (t1) ----------------
__global__ __launch_bounds__(256) void k_cstat(const float* srcf, const ushort_t* srch, int isbf,
      int C, int HWn, int Bn, int S, float* stats){
  int c = blockIdx.x % C; int s = blockIdx.x / C;
  float sum=0.f, sq=0.f;
  for(int b=0;b<Bn;b++){
    size_t base=((size_t)b*C+c)*HWn;
    for(int i=s*256+threadIdx.x; i<HWn; i+=S*256){
      float v = isbf ? bf2f(srch[base+i]) : srcf[base+i];
      sum+=v; sq+=v*v;
    }
  }
  for(int o=32;o;o>>=1){ sum+=__shfl_down(sum,o,64); sq+=__shfl_down(sq,o,64); }
  __shared__ float ls[4], lq[4];
  int wid=threadIdx.x>>6;
  if((threadIdx.x&63)==0){ ls[wid]=sum; lq[wid]=sq; }
  __syncthreads();
  if(threadIdx.x==0){
    atomicAdd(&stats[2*c],   ls[0]+ls[1]+ls[2]+ls[3]);
    atomicAdd(&stats[2*c+1], lq[0]+lq[1]+lq[2]+lq[3]);
  }
}

__global__ __launch_bounds__(64) void k_csb(const float* stats, const void* g, const void* b,
      const float* dfl, float invN, float* scale, float* bias){
  int c=threadIdx.x; if(c>=NC) return;
  int isbf = dfl[0]>0.5f;
  float mean=stats[2*c]*invN; float var=stats[2*c+1]*invN - mean*mean;
  float s=ldg_(g,c,isbf)*rsqrtf(var+1e-5f);
  scale[c]=s; bias[c]=ldg_(b,c,isbf)-s*mean;
}

// ---------------- CHANGE ----------------
__global__ __launch_bounds__(256) void k_change(const ushort_t* h2h,
      const float* wc2, const float* sc, const float* bi, float* CH){
  int p=blockIdx.x*256+threadIdx.x;
  int b=p>>14; int rem=p&16383; int i=rem>>7; int j=rem&127;
  float acc=0.f;
  for(int ic=0;ic<NC;ic++){
    size_t base=((size_t)(b*NC+ic)*HH + 2*i)*WW + 2*j;
    float s=sc[ic], t=bi[ic];
    #pragma unroll
    for(int ki=0;ki<2;ki++)
      #pragma unroll
      for(int kj=0;kj<2;kj++){
        float v= bf2f(h2h[base+(size_t)ki*WW+kj]);
        acc += tanhf_(s*v+t)*wc2[ic*4+ki*2+kj];
      }
  }
  CH[p]=sigm_(acc);
}

// ---------------- t1 ----------------
__global__ __launch_bounds__(256) void k_cm1(const void* x, const float* dfl, const float* w, float* t1){
  int isbf = dfl[0]>0.5f;
  int p=blockIdx.x*256+threadIdx.x;
  int b=p>>14; int rem=p&16383; int i=rem>>7; int j=rem&127;
  float v[6][2][2];
  #pragma unroll
  for(int d=0;d<6;d++)
    #pragma unroll
    for(int ki=0;ki<2;ki++)
      #pragma unroll
      for(int kj=0;kj<2;kj++)
        v[d][ki][kj]=ldg_(x, ((size_t)(b*6+d)*HH + 2*i+ki)*WW + 2*j+kj, isbf);
  for(int oc=0;oc<NC;oc++){
    int g=oc>>4;
    float a=0.f;
    #pragma unroll
    for(int icl=0;icl<2;icl++)
      #pragma unroll
      for(int ki=0;ki<2;ki++)
        #pragma unroll
        for(int kj=0;kj<2;kj++)
          a += v[2*g+icl][ki][kj]*w[((oc*2+icl)*2+ki)*2+kj];
    t1[((size_t)(b*NC+oc)*HW2) + rem]=a;
  }
}

// ---------------- t2: 16x16 tiles, group in z ----------------
__global__ __launch_bounds__(256) void k_cm2(const float* t1, const float* sc, const float* bi,
        const float* wct, float* t2){
  __shared__ float as[16][20][21];
  int b=blockIdx.y, g=blockIdx.z;
  int ti=blockIdx.x/9, tj=blockIdx.x%9;
  int i0=ti*16, j0=tj*16;
  int ty=threadIdx.x>>4, tx=threadIdx.x&15;
  for(int idx=threadIdx.x; idx<6400; idx+=256){
    int i=idx/400; int rem=idx-i*400; int r=rem/20; int cc=rem-r*20;
    int cg=g*16+i;
    int y=i0-2+r, xx=j0-2+cc;
    float v=0.f;
    if(y>=0 && y<H2 && xx>=0 && xx<H2)
      v = tanhf_(sc[cg]*t1[((size_t)(b*NC+cg)*H2 + y)*H2 + xx] + bi[cg]);
    as[i][r][cc]=v;
  }
  __syncthreads();
  float acc[16];
  #pragma unroll
  for(int o=0;o<16;o++) acc[o]=0.f;
  for(int i=0;i<16;i++){
    float p[3][3];
    #pragma unroll
    for(int ki=0;ki<3;ki++)
      #pragma unroll
      for(int kj=0;kj<3;kj++) p[ki][kj]=as[i][ty+ki][tx+kj];
    #pragma unroll
    for(int o=0;o<16;o++){
      const float* wp=&wct[((size_t)(g*16+o)*16+i)*9];
      float a=0.f;
      #pragma unroll
      for(int q=0;q<9;q++) a += p[q/3][q%3]*wp[q];
      acc[o]+=a;
    }
  }
  int ii=i0+ty, jj=j0+tx;
  if(ii<130 && jj<130){
    #pragma unroll
    for(int o=0;o<16;o++)
      t2[((size_t)(b*NC+g*16+o)*130 + ii)*130 + jj]=tanhf_(acc[o]);
  }
}

// ---------------- xm: group in z ----------------
__global__ __launch_bounds__(256) void k_cm3(const float* t2, const float* w, float* xm){
  __shared__ float ts[16][18][20];
  int b=blockIdx.y, g=blockIdx.z;
  int ti=blockIdx.x>>3, tj=blockIdx.x&7;
  int i0=ti*16, j0=tj*16;
  int ty=threadIdx.x>>4, tx=threadIdx.x&15;
  for(int idx=threadIdx.x; idx<16*18*18; idx+=256){
    int i=idx/324; int rem=idx-i*324; int r=rem/18; int cc=rem-r*18;
    int cg=g*16+i;
    ts[i][r][cc]=t2[((size_t)(b*NC+cg)*130 + i0+r)*130 + j0+cc];
  }
  __syncthreads();
  float acc[2]={0.f,0.f};
  for(int icl=0;icl<16;icl++){
    float p[3][3];
    #pragma unroll
    for(int ki=0;ki<3;ki++)
      #pragma unroll
      for(int kj=0;kj<3;kj++) p[ki][kj]=ts[icl][ty+ki][tx+kj];
    #pragma unroll
    for(int ol=0;ol<2;ol++){
      int oc=2*g+ol;
      const float* wp=&w[((size_t)oc*16+icl)*9];
      float a=0.f;
      #pragma unroll
      for(int q=0;q<9;q++) a += p[q/3][q%3]*wp[q];
      acc[ol]+=a;
    }
  }
  int ii=i0+ty, jj=j0+tx;
  #pragma unroll
  for(int ol=0;ol<2;ol++)
    xm[((size_t)(b*6+2*g+ol)*H2 + ii)*H2 + jj]=tanhf_(acc[ol]);
}

// ---------------- final ----------------
__global__ __launch_bounds__(256) void k_final(const float* xm, const float* CH, const float* w1,
      const float* w2, const float* sc, const float* bi, const float* dfl, void* outp){
  int isbf = dfl[0]>0.5f;
  int p=blockIdx.x*256+threadIdx.x;
  int b=p>>14; int rem=p&16383;
  float v[6];
  #pragma unroll
  for(int d=0;d<6;d++) v[d]=xm[((size_t)(b*6+d)*HW2)+rem];
  float born[6]={0.f,0.f,0.f,0.f,0.f,0.f};
  for(int c=0;c<NC;c++){
    float y=0.f;
    #pragma unroll
    for(int d=0;d<6;d++) y+=w1[c*6+d]*v[d];
    float a=tanhf_(sc[c]*y+bi[c]);
    #pragma unroll
    for(int d=0;d<6;d++) born[d]+=w2[d*NC+c]*a;
  }
  float C=CH[p];
  #pragma unroll
  for(int d=0;d<6;d++){
    float o=v[d]*(1.f-C)+C*born[d];
    if(d<3) o=sigm_(o);
    size_t id=((size_t)(b*6+d)*HW2)+rem;
    if(isbf) ((ushort_t*)outp)[id]=f2bf(o); else ((float*)outp)[id]=o;
  }
}

extern "C" void kernel_launch(void* const* d_in, const int* in_sizes, int n_in,
                              void* d_out, int out_size, void* d_ws, size_t ws_size,
                              hipStream_t stream){
  (void)in_sizes; (void)n_in; (void)out_size; (void)ws_size;
  const ushort_t* x    = (const ushort_t*)d_in[0];
  const ushort_t* cew1 = (const ushort_t*)d_in[1];
  const void*     ceg  = d_in[2];
  const void*     ceb  = d_in[3];
  const ushort_t* cew2 = (const ushort_t*)d_in[4];
  const ushort_t* mdct = (const ushort_t*)d_in[5];
  const ushort_t* mdc1 = (const ushort_t*)d_in[6];
  const void*     mdg  = d_in[7];
  const void*     mdb  = d_in[8];
  const ushort_t* mdc2 = (const ushort_t*)d_in[9];
  const ushort_t* cmw1 = (const ushort_t*)d_in[10];
  const void*     cmg  = d_in[11];
  const void*     cmb  = d_in[12];
  const ushort_t* cmct = (const ushort_t*)d_in[13];
  const ushort_t* cmc2 = (const ushort_t*)d_in[14];
  const ushort_t* bow1 = (const ushort_t*)d_in[15];
  const void*     bog  = d_in[16];
  const void*     bob  = d_in[17];
  const ushort_t* bow2 = (const ushort_t*)d_in[18];
  float* ws = (float*)d_ws;

  const long OW_mdct=0, OW_mdc1=4320, OW_cew1=25056, OW_cew2=25344, OW_mdc2=25392,
             OW_cmw1=25584, OW_cmct=25968, OW_cmc2=32880, OW_bow1=33744, OW_bow2=34032;
  const long OFF_STATS=34320;
  const long ST_xmom=OFF_STATS+0,  ST_cesc=OFF_STATS+64,  ST_cebi=OFF_STATS+112,
             ST_h2  =OFF_STATS+160, ST_mdsc=OFF_STATS+256, ST_mdbi=OFF_STATS+304,
             ST_t1  =OFF_STATS+352, ST_cmsc=OFF_STATS+448, ST_cmbi=OFF_STATS+496,
             ST_xmm =OFF_STATS+544, ST_bosc=OFF_STATS+608, ST_bobi=OFF_STATS+656,
             ST_FLAG=OFF_STATS+960;
  const long OFF_WB2 = OFF_STATS + 1024;
  const long OFF_WB1 = OFF_WB2 + 13824;
  const long OFF_E   = OFF_WB1 + 6912;
  const long OFF_H2  = OFF_E + 524288L;        // h2 bf16 planar: 12582912 float-slots
  const long OFF_D   = OFF_H2 + 12582912L;     // h1 channels-last bf16, later t1/t2/xm/CH
  const long OFF_T1=OFF_D, OFF_T2=OFF_D+6291456L, OFF_XM=OFF_D+12781056L, OFF_CH=OFF_D+13567488L;

  ushort_t* h1cl = (ushort_t*)(ws + OFF_D);
  ushort_t* h2h  = (ushort_t*)(ws + OFF_H2);
  ushort_t* wb2  = (ushort_t*)(ws + OFF_WB2);
  ushort_t* wb1  = (ushort_t*)(ws + OFF_WB1);
  const float* dfl = ws + ST_FLAG;

  (void)hipMemsetAsync(ws + OFF_STATS, 0, 1024*sizeof(float), stream);
  hipLaunchKernelGGL(k_detect, dim3(1), 256, 0, stream, x, ws+ST_FLAG);

  WC wc;
  const ushort_t* srcs[10] = {mdct,mdc1,cew1,cew2,mdc2,cmw1,cmct,cmc2,bow1,bow2};
  const int offs[10] = {(int)OW_mdct,(int)OW_mdc1,(int)OW_cew1,(int)OW_cew2,(int)OW_mdc2,
                        (int)OW_cmw1,(int)OW_cmct,(int)OW_cmc2,(int)OW_bow1,(int)OW_bow2};
  const int cnts[10] = {4320,20736,288,48,192,384,6912,864,288,288};
  for(int i=0;i<10;i++){ wc.src[i]=srcs[i]; wc.off[i]=offs[i]; wc.n[i]=cnts[i]; }
  hipLaunchKernelGGL(k_wcvt, dim3(81,10), 256, 0, stream, wc, ws, dfl);
  hipLaunchKernelGGL(k_wprep, dim3(21), 256, 0, stream, ws+OW_mdc1, ws+OW_mdct, wb2, wb1);

  // compenv
  hipLaunchKernelGGL(k_mom, dim3(256), 256, 0, stream, (const void*)x, dfl, 0, 16, B8*HWp, ws+ST_xmom);
  hipLaunchKernelGGL(k_msb, dim3(1), 64, 0, stream, ws+ST_xmom, ws+OW_cew1, ceg, ceb, dfl,
                     1.f/(float)(B8*HWp), ws+ST_cesc, ws+ST_cebi);
  hipLaunchKernelGGL(k_env, dim3(2048), 256, 0, stream, (const void*)x, dfl, ws+OW_cew1, ws+OW_cew2,
                     ws+ST_cesc, ws+ST_cebi, ws+OFF_E);

  // md chain (MFMA, h1 channels-last, fused h2 stats)
  hipLaunchKernelGGL(k_h1m, dim3(289,8), 256, 0, stream, (const void*)x, dfl, ws+OFF_E, wb1, h1cl);
  hipLaunchKernelGGL(k_h2m, dim3(256,8), 256, 0, stream, h1cl, wb2, h2h, ws+ST_h2);
  hipLaunchKernelGGL(k_csb, dim3(1), 64, 0, stream, ws+ST_h2, mdg, mdb, dfl, 1.f/(float)(B8*HWp),
                     ws+ST_mdsc, ws+ST_mdbi);
  hipLaunchKernelGGL(k_change, dim3(512), 256, 0, stream, h2h, ws+OW_mdc2,
                     ws+ST_mdsc, ws+ST_mdbi, ws+OFF_CH);

  // cm chain (h1 region dead; t1/t2/xm/CH overlay it)
  hipLaunchKernelGGL(k_cm1, dim3(512), 256, 0, stream, (const void*)x, dfl, ws+OW_cmw1, ws+OFF_T1);
  hipLaunchKernelGGL(k_cstat, dim3(48*8), 256, 0, stream, ws+OFF_T1, (const ushort_t*)nullptr, 0,
                     NC, HW2, B8, 8, ws+ST_t1);
  hipLaunchKernelGGL(k_csb, dim3(1), 64, 0, stream, ws+ST_t1, cmg, cmb, dfl, 1.f/(float)(B8*HW2),
                     ws+ST_cmsc, ws+ST_cmbi);
  hipLaunchKernelGGL(k_cm2, dim3(81,8,3), 256, 0, stream, ws+OFF_T1, ws+ST_cmsc, ws+ST_cmbi,
                     ws+OW_cmct, ws+OFF_T2);
  hipLaunchKernelGGL(k_cm3, dim3(64,8,3), 256, 0, stream, ws+OFF_T2, ws+OW_cmc2, ws+OFF_XM);

  // born + blend
  hipLaunchKernelGGL(k_mom, dim3(128), 256, 0, stream, (const void*)(ws+OFF_XM), (const float*)nullptr, 0,
                     14, B8*HW2, ws+ST_xmm);
  hipLaunchKernelGGL(k_msb, dim3(1), 64, 0, stream, ws+ST_xmm, ws+OW_bow1, bog, bob, dfl,
                     1.f/(float)(B8*HW2), ws+ST_bosc, ws+ST_bobi);
  hipLaunchKernelGGL(k_final, dim3(512), 256, 0, stream, ws+OFF_XM, ws+OFF_CH, ws+OW_bow1,
                     ws+OW_bow2, ws+ST_bosc, ws+ST_bobi, dfl, d_out);
}

// Round 8
// 483.058 us; speedup vs baseline: 1.0291x; 1.0291x over previous
//
#include <hip/hip_runtime.h>
#include <stdint.h>

typedef unsigned short ushort_t;

#define B8  8
#define D6  6
#define NC  48
#define HH  256
#define WW  256
#define HWp 65536
#define H2  128
#define HW2 16384

__device__ __constant__ int c_T0[8] = {0,1,1,1,0,-1,-1,-1};
__device__ __constant__ int c_T1[8] = {1,1,0,-1,-1,-1,0,1};

__device__ inline float bf2f(ushort_t u){ union{unsigned int i; float f;} w; w.i = ((unsigned int)u)<<16; return w.f; }
__device__ inline ushort_t f2bf(float f){ union{float f; unsigned int i;} w; w.f=f; unsigned int xx=w.i;
  return (ushort_t)((xx + 0x7fffu + ((xx>>16)&1u)) >> 16); }
__device__ inline float tanhf_(float x){ float e=__expf(2.f*x); return 1.f - 2.f/(e+1.f); }
__device__ inline float sigm_(float x){ return 1.f/(1.f+__expf(-x)); }
__device__ inline float ldg_(const void* p, size_t i, int isbf){
  return isbf ? bf2f(((const ushort_t*)p)[i]) : ((const float*)p)[i];
}

typedef short short8 __attribute__((ext_vector_type(8)));
typedef float f4 __attribute__((ext_vector_type(4)));
typedef ushort_t us4 __attribute__((ext_vector_type(4)));
typedef ushort_t us8 __attribute__((ext_vector_type(8)));
union AB { short8 s; us4 h[2]; us8 u; };

// ---------------- dtype detection ----------------
__global__ __launch_bounds__(256) void k_detect(const ushort_t* x, float* flag){
  int t=threadIdx.x; int cnt=0;
  for(int i=t;i<4096;i+=256){
    ushort_t u=x[2*i];
    int e=(u>>7)&0xff;
    if(e>=100 && e<=150) cnt++;
  }
  for(int o=32;o;o>>=1) cnt+=__shfl_down(cnt,o,64);
  __shared__ int sh4[4];
  if((t&63)==0) sh4[t>>6]=cnt;
  __syncthreads();
  if(t==0){ int tot=sh4[0]+sh4[1]+sh4[2]+sh4[3]; flag[0] = (tot>=2048)?1.f:0.f; }
}

// ---------------- weight conversion to fp32 ----------------
struct WC { const ushort_t* src[10]; int off[10]; int n[10]; };

__global__ __launch_bounds__(256) void k_wcvt(WC wc, float* dst, const float* dfl){
  int isbf = dfl[0]>0.5f;
  int t = blockIdx.y; int n = wc.n[t]; const ushort_t* s = wc.src[t]; float* d = dst + wc.off[t];
  for(int i = blockIdx.x*256 + threadIdx.x; i < n; i += gridDim.x*256)
    d[i] = isbf ? bf2f(s[i]) : ((const float*)s)[i];
}

// ---------------- MFMA weight prep ----------------
__global__ __launch_bounds__(256) void k_wprep(const float* w2src, const float* w1src,
                                               ushort_t* wb2, ushort_t* wb1){
  int t = blockIdx.x*256+threadIdx.x;
  if(t<3456){
    int lane=t&63; int rest=t>>6;
    int ks=rest&1; int g=rest>>1; int tap=g%9; int nt=g/9;
    int oc=nt*16+(lane&15); int icb=ks*32+((lane>>4)*8);
    #pragma unroll
    for(int j=0;j<8;j++){
      int ic=icb+j;
      float v = (ic<48) ? w2src[(oc*48+ic)*9+tap] : 0.f;
      wb2[(size_t)t*8+j]=f2bf(v);
    }
  } else if(t<5184){
    int tt=t-3456; int lane=tt&63; int g=tt>>6; int tap=g%9; int nt=g/9;
    int oc=nt*16+(lane&15); int icb=(lane>>4)*8;
    #pragma unroll
    for(int j=0;j<8;j++){
      int ic=icb+j;
      float v = (ic<10) ? w1src[(oc*10+ic)*9+tap] : 0.f;
      wb1[(size_t)tt*8+j]=f2bf(v);
    }
  }
}

// ---------------- 6-channel moment reduction ----------------
__global__ __launch_bounds__(256) void k_mom(const void* src, const float* dfl, int isbfc,
                                             int sh, int npix, float* out){
  int isbf = dfl ? (dfl[0]>0.5f) : isbfc;
  float vals[27];
  #pragma unroll
  for(int i=0;i<27;i++) vals[i]=0.f;
  int stride = gridDim.x*256;
  int msk = (1<<sh)-1;
  for(int p = blockIdx.x*256+threadIdx.x; p < npix; p += stride){
    int b = p >> sh; int hw = p & msk;
    float v[6];
    #pragma unroll
    for(int d=0; d<6; d++){
      size_t idx = (((size_t)(b*6+d))<<sh) + hw;
      v[d] = ldg_(src, idx, isbf);
    }
    int q=6;
    #pragma unroll
    for(int d=0;d<6;d++){
      vals[d]+=v[d];
      #pragma unroll
      for(int e=d;e<6;e++){ vals[q] += v[d]*v[e]; q++; }
    }
  }
  __shared__ float red[4][27];
  int wid=threadIdx.x>>6, lane=threadIdx.x&63;
  #pragma unroll
  for(int i=0;i<27;i++){
    float v=vals[i];
    for(int o=32;o;o>>=1) v+=__shfl_down(v,o,64);
    if(lane==0) red[wid][i]=v;
  }
  __syncthreads();
  if(threadIdx.x<27)
    atomicAdd(&out[threadIdx.x],
      red[0][threadIdx.x]+red[1][threadIdx.x]+red[2][threadIdx.x]+red[3][threadIdx.x]);
}

__global__ __launch_bounds__(64) void k_msb(const float* mom, const float* W1,
      const void* g, const void* b, const float* dfl, float invN, float* scale, float* bias){
  int c = threadIdx.x; if(c>=NC) return;
  int isbf = dfl[0]>0.5f;
  const int st[6]={0,6,11,15,18,20};
  float wr[6];
  #pragma unroll
  for(int d=0;d<6;d++) wr[d]=W1[c*6+d];
  float mean=0.f;
  #pragma unroll
  for(int d=0;d<6;d++) mean += wr[d]*mom[d];
  mean *= invN;
  float e2=0.f;
  #pragma unroll
  for(int d=0;d<6;d++){
    #pragma unroll
    for(int e=d;e<6;e++){
      float mm = mom[6 + st[d] + (e-d)];
      e2 += wr[d]*wr[e]*((e==d)?1.f:2.f)*mm;
    }
  }
  e2 *= invN;
  float var = e2 - mean*mean;
  float sc = ldg_(g,c,isbf) * rsqrtf(var + 1e-5f);
  scale[c]=sc; bias[c]= ldg_(b,c,isbf) - sc*mean;
}

// ---------------- compenv ----------------
__global__ __launch_bounds__(256) void k_env(const void* x, const float* dfl,
      const float* w1, const float* w2, const float* sc, const float* bi, float* e){
  int isbf = dfl[0]>0.5f;
  int p = blockIdx.x*256+threadIdx.x;
  int b = p >> 16; int hw = p & 65535;
  float v[6];
  #pragma unroll
  for(int d=0; d<6; d++) v[d]=ldg_(x,(size_t)(b*6+d)*HWp + hw, isbf);
  float acc=0.f;
  for(int c=0;c<NC;c++){
    float y=0.f;
    #pragma unroll
    for(int d=0;d<6;d++) y += w1[c*6+d]*v[d];
    acc += w2[c]*tanhf_(sc[c]*y + bi[c]);
  }
  e[(size_t)b*HWp + hw]=acc;
}

// ---------------- h1 (MFMA) -> channels-last bf16 [8][258][258][48] ----------------
__global__ __launch_bounds__(256) void k_h1m(const void* x, const float* dfl, const float* e,
      const ushort_t* wb1, ushort_t* h1cl){
  __shared__ __attribute__((aligned(16))) ushort_t tile[324*24];  // [pix 18x18][icdim 24]
  int isbf = dfl[0]>0.5f;
  int b = blockIdx.y;
  int ti = blockIdx.x/17, tj = blockIdx.x%17;
  int i0 = ti*16, j0 = tj*16;
  {
    us8 z;
    #pragma unroll
    for(int j=0;j<8;j++) z[j]=0;
    us8* tp=(us8*)tile;
    for(int idx=threadIdx.x; idx<972; idx+=256) tp[idx]=z;
  }
  __syncthreads();
  for(int idx=threadIdx.x; idx<3240; idx+=256){
    int pix = idx/10, ic = idx-pix*10;
    int r = pix/18, c = pix-r*18;
    int gy = i0-2+r, gx = j0-2+c;
    float v = 0.f;
    if(gy>=0 && gy<HH && gx>=0 && gx<WW){
      if(ic<2) v = ldg_(x, ((size_t)(b*6+ic)*HH + gy)*WW + gx, isbf);
      else { int k=ic-2;
        int yy=(gy + c_T1[k]) & 255; int xx=(gx - c_T0[k]) & 255;
        v = e[((size_t)b*HH + yy)*WW + xx]; }
    }
    tile[pix*24+ic]=f2bf(v);
  }
  __syncthreads();
  int lane = threadIdx.x&63, w = threadIdx.x>>6;
  int n = lane&15, quad = lane>>4;
  int qoff = (quad<2) ? quad*8 : 16;   // quads 2,3 -> zero slots (B=0 there)
  f4 acc[4][3];
  #pragma unroll
  for(int a=0;a<4;a++)
    #pragma unroll
    for(int c=0;c<3;c++) acc[a][c]=(f4){0.f,0.f,0.f,0.f};
  for(int tap=0; tap<9; tap++){
    int ki=tap/3, kj=tap%3;
    AB Bf[3];
    #pragma unroll
    for(int nt=0;nt<3;nt++) Bf[nt].u = *(const us8*)&wb1[((size_t)((nt*9+tap)*64+lane))*8];
    #pragma unroll
    for(int yy=0; yy<4; yy++){
      int y = w*4 + yy;
      AB a; a.u = *(const us8*)&tile[((y+ki)*18 + n + kj)*24 + qoff];
      #pragma unroll
      for(int nt=0;nt<3;nt++)
        acc[yy][nt] = __builtin_amdgcn_mfma_f32_16x16x32_bf16(a.s, Bf[nt].s, acc[yy][nt], 0,0,0);
    }
  }
  #pragma unroll
  for(int yy=0;yy<4;yy++){
    int Y = i0 + w*4 + yy;
    if(Y>=258) continue;
    #pragma unroll
    for(int nt=0;nt<3;nt++){
      int oc = nt*16 + n;
      #pragma unroll
      for(int r=0;r<4;r++){
        int X = j0 + quad*4 + r;
        if(X<258)
          h1cl[(((size_t)b*258 + Y)*258 + X)*48 + oc] = f2bf(tanhf_(acc[yy][nt][r]));
      }
    }
  }
}

// ---------------- h2 (MFMA) -> planar bf16 [8][48][256][256], fused BN stats ----------------
// LDS tile packed at 48ch/pixel (96B); staged via async global_load_lds width=16
// (wave-uniform LDS base + lane*16, contiguous chunk order). Dead-K lanes read a
// 32B zeroed LDS tail (uniform broadcast). 2048 chunks = 32768B; real data 1944.
__global__ __launch_bounds__(256) void k_h2m(const ushort_t* h1cl, const ushort_t* wb2,
      ushort_t* h2h, float* stats){
  __shared__ __attribute__((aligned(16))) ushort_t tile[16416];  // 32768B + 32B ztail + pad
  __shared__ float red[4][3][16][2];
  int b = blockIdx.y;
  int ti = blockIdx.x>>4, tj = blockIdx.x&15;
  int i0 = ti*16, j0 = tj*16;
  int lane = threadIdx.x&63, w = threadIdx.x>>6;
  // async staging: 8 rounds x 4 waves x 64 lanes x 16B
  #pragma unroll
  for(int it=0; it<8; it++){
    int chunk = (it*4 + w)*64 + lane;            // 0..2047
    int cpix = chunk/6, cq = chunk - cpix*6;
    if(chunk>=1944){ cpix=0; cq=0; }             // harmless dup; lands in garbage zone
    int r = cpix/18, cc = cpix - r*18;
    const ushort_t* src = &h1cl[(((size_t)b*258 + i0+r)*258 + (j0+cc))*48 + cq*8];
    __builtin_amdgcn_global_load_lds(
        (const __attribute__((address_space(1))) unsigned int*)src,
        (__attribute__((address_space(3))) unsigned int*)&tile[(it*4 + w)*512],
        16, 0, 0);
  }
  if(threadIdx.x<16) tile[16384+threadIdx.x]=0;  // zero tail for dead-K reads
  __syncthreads();
  int n = lane&15, quad = lane>>4;
  f4 acc[4][3];
  #pragma unroll
  for(int a=0;a<4;a++)
    #pragma unroll
    for(int c=0;c<3;c++) acc[a][c]=(f4){0.f,0.f,0.f,0.f};
  for(int tap=0; tap<9; tap++){
    int ki=tap/3, kj=tap%3;
    AB Bf[3][2];
    #pragma unroll
    for(int nt=0;nt<3;nt++)
      #pragma unroll
      for(int ks=0;ks<2;ks++)
        Bf[nt][ks].u = *(const us8*)&wb2[((size_t)(((nt*9+tap)*2+ks)*64+lane))*8];
    #pragma unroll
    for(int yy=0; yy<4; yy++){
      int y = w*4 + yy;
      int pix = (y+ki)*18 + n + kj;
      AB a0, a1;
      a0.u = *(const us8*)&tile[pix*48 + quad*8];
      a1.u = (quad<2) ? *(const us8*)&tile[pix*48 + 32 + quad*8]
                      : *(const us8*)&tile[16384];
      #pragma unroll
      for(int nt=0;nt<3;nt++){
        acc[yy][nt] = __builtin_amdgcn_mfma_f32_16x16x32_bf16(a0.s, Bf[nt][0].s, acc[yy][nt], 0,0,0);
        acc[yy][nt] = __builtin_amdgcn_mfma_f32_16x16x32_bf16(a1.s, Bf[nt][1].s, acc[yy][nt], 0,0,0);
      }
    }
  }
  float s[3]={0.f,0.f,0.f}, q[3]={0.f,0.f,0.f};
  #pragma unroll
  for(int yy=0;yy<4;yy++){
    int Y = i0 + w*4 + yy;
    #pragma unroll
    for(int nt=0;nt<3;nt++){
      int oc = nt*16 + n;
      size_t base = ((size_t)(b*NC+oc)*HH + Y)*WW + j0 + quad*4;
      us4 u;
      #pragma unroll
      for(int r=0;r<4;r++){
        float v=tanhf_(acc[yy][nt][r]);
        u[r]=f2bf(v);
        float vb=bf2f(u[r]);
        s[nt]+=vb; q[nt]+=vb*vb;
      }
      *(us4*)&h2h[base] = u;
    }
  }
  #pragma unroll
  for(int nt=0;nt<3;nt++){
    s[nt]+=__shfl_xor(s[nt],16,64); s[nt]+=__shfl_xor(s[nt],32,64);
    q[nt]+=__shfl_xor(q[nt],16,64); q[nt]+=__shfl_xor(q[nt],32,64);
  }
  if(quad==0){
    #pragma unroll
    for(int nt=0;nt<3;nt++){ red[w][nt][n][0]=s[nt]; red[w][nt][n][1]=q[nt]; }
  }
  __syncthreads();
  if(threadIdx.x<48){
    int oc=threadIdx.x; int nt=oc>>4, nn=oc&15;
    float S=red[0][nt][nn][0]+red[1][nt][nn][0]+red[2][nt][nn][0]+red[3][nt][nn][0];
    float Q=red[0][nt][nn][1]+red[1][nt][nn][1]+red[2][nt][nn][1]+red[3][nt][nn][1];
    atomicAdd(&stats[2*oc],S); atomicAdd(&stats[2*oc+1],Q);
  }
}

// ---------------- per-channel sum/sumsq (t1) ----------------
__global__ __launch_bounds__(256) void k_cstat(const float* srcf, const ushort_t* srch, int isbf,
      int C, int HWn, int Bn, int S, float* stats){
  int c = blockIdx.x % C; int s = blockIdx.x / C;
  float sum=0.f, sq=0.f;
  for(int b=0;b<Bn;b++){
    size_t base=((size_t)b*C+c)*HWn;
    for(int i=s*256+threadIdx.x; i<HWn; i+=S*256){
      float v = isbf ? bf2f(srch[base+i]) : srcf[base+i];
      sum+=v; sq+=v*v;
    }
  }
  for(int o=32;o;o>>=1){ sum+=__shfl_down(sum,o,64); sq+=__shfl_down(sq,o,64); }
  __shared__ float ls[4], lq[4];
  int wid=threadIdx.x>>6;
  if((threadIdx.x&63)==0){ ls[wid]=sum; lq[wid]=sq; }
  __syncthreads();
  if(threadIdx.x==0){
    atomicAdd(&stats[2*c],   ls[0]+ls[1]+ls[2]+ls[3]);
    atomicAdd(&stats[2*c+1], lq[0]+lq[1]+lq[2]+lq[3]);
  }
}

__global__ __launch_bounds__(64) void k_csb(const float* stats, const void* g, const void* b,
      const float* dfl, float invN, float* scale, float* bias){
  int c=threadIdx.x; if(c>=NC) return;
  int isbf = dfl[0]>0.5f;
  float mean=stats[2*c]*invN; float var=stats[2*c+1]*invN - mean*mean;
  float s=ldg_(g,c,isbf)*rsqrtf(var+1e-5f);
  scale[c]=s; bias[c]=ldg_(b,c,isbf)-s*mean;
}

// ---------------- CHANGE ----------------
__global__ __launch_bounds__(256) void k_change(const ushort_t* h2h,
      const float* wc2, const float* sc, const float* bi, float* CH){
  int p=blockIdx.x*256+threadIdx.x;
  int b=p>>14; int rem=p&16383; int i=rem>>7; int j=rem&127;
  float acc=0.f;
  for(int ic=0;ic<NC;ic++){
    size_t base=((size_t)(b*NC+ic)*HH + 2*i)*WW + 2*j;
    float s=sc[ic], t=bi[ic];
    #pragma unroll
    for(int ki=0;ki<2;ki++)
      #pragma unroll
      for(int kj=0;kj<2;kj++){
        float v= bf2f(h2h[base+(size_t)ki*WW+kj]);
        acc += tanhf_(s*v+t)*wc2[ic*4+ki*2+kj];
      }
  }
  CH[p]=sigm_(acc);
}

// ---------------- t1 ----------------
__global__ __launch_bounds__(256) void k_cm1(const void* x, const float* dfl, const float* w, float* t1){
  int isbf = dfl[0]>0.5f;
  int p=blockIdx.x*256+threadIdx.x;
  int b=p>>14; int rem=p&16383; int i=rem>>7; int j=rem&127;
  float v[6][2][2];
  #pragma unroll
  for(int d=0;d<6;d++)
    #pragma unroll
    for(int ki=0;ki<2;ki++)
      #pragma unroll
      for(int kj=0;kj<2;kj++)
        v[d][ki][kj]=ldg_(x, ((size_t)(b*6+d)*HH + 2*i+ki)*WW + 2*j+kj, isbf);
  for(int oc=0;oc<NC;oc++){
    int g=oc>>4;
    float a=0.f;
    #pragma unroll
    for(int icl=0;icl<2;icl++)
      #pragma unroll
      for(int ki=0;ki<2;ki++)
        #pragma unroll
        for(int kj=0;kj<2;kj++)
          a += v[2*g+icl][ki][kj]*w[((oc*2+icl)*2+ki)*2+kj];
    t1[((size_t)(b*NC+oc)*HW2) + rem]=a;
  }
}

// ---------------- t2: 16x16 tiles, group in z ----------------
__global__ __launch_bounds__(256) void k_cm2(const float* t1, const float* sc, const float* bi,
        const float* wct, float* t2){
  __shared__ float as[16][20][21];
  int b=blockIdx.y, g=blockIdx.z;
  int ti=blockIdx.x/9, tj=blockIdx.x%9;
  int i0=ti*16, j0=tj*16;
  int ty=threadIdx.x>>4, tx=threadIdx.x&15;
  for(int idx=threadIdx.x; idx<6400; idx+=256){
    int i=idx/400; int rem=idx-i*400; int r=rem/20; int cc=rem-r*20;
    int cg=g*16+i;
    int y=i0-2+r, xx=j0-2+cc;
    float v=0.f;
    if(y>=0 && y<H2 && xx>=0 && xx<H2)
      v = tanhf_(sc[cg]*t1[((size_t)(b*NC+cg)*H2 + y)*H2 + xx] + bi[cg]);
    as[i][r][cc]=v;
  }
  __syncthreads();
  float acc[16];
  #pragma unroll
  for(int o=0;o<16;o++) acc[o]=0.f;
  for(int i=0;i<16;i++){
    float p[3][3];
    #pragma unroll
    for(int ki=0;ki<3;ki++)
      #pragma unroll
      for(int kj=0;kj<3;kj++) p[ki][kj]=as[i][ty+ki][tx+kj];
    #pragma unroll
    for(int o=0;o<16;o++){
      const float* wp=&wct[((size_t)(g*16+o)*16+i)*9];
      float a=0.f;
      #pragma unroll
      for(int q=0;q<9;q++) a += p[q/3][q%3]*wp[q];
      acc[o]+=a;
    }
  }
  int ii=i0+ty, jj=j0+tx;
  if(ii<130 && jj<130){
    #pragma unroll
    for(int o=0;o<16;o++)
      t2[((size_t)(b*NC+g*16+o)*130 + ii)*130 + jj]=tanhf_(acc[o]);
  }
}

// ---------------- xm: group in z ----------------
__global__ __launch_bounds__(256) void k_cm3(const float* t2, const float* w, float* xm){
  __shared__ float ts[16][18][20];
  int b=blockIdx.y, g=blockIdx.z;
  int ti=blockIdx.x>>3, tj=blockIdx.x&7;
  int i0=ti*16, j0=tj*16;
  int ty=threadIdx.x>>4, tx=threadIdx.x&15;
  for(int idx=threadIdx.x; idx<16*18*18; idx+=256){
    int i=idx/324; int rem=idx-i*324; int r=rem/18; int cc=rem-r*18;
    int cg=g*16+i;
    ts[i][r][cc]=t2[((size_t)(b*NC+cg)*130 + i0+r)*130 + j0+cc];
  }
  __syncthreads();
  float acc[2]={0.f,0.f};
  for(int icl=0;icl<16;icl++){
    float p[3][3];
    #pragma unroll
    for(int ki=0;ki<3;ki++)
      #pragma unroll
      for(int kj=0;kj<3;kj++) p[ki][kj]=ts[icl][ty+ki][tx+kj];
    #pragma unroll
    for(int ol=0;ol<2;ol++){
      int oc=2*g+ol;
      const float* wp=&w[((size_t)oc*16+icl)*9];
      float a=0.f;
      #pragma unroll
      for(int q=0;q<9;q++) a += p[q/3][q%3]*wp[q];
      acc[ol]+=a;
    }
  }
  int ii=i0+ty, jj=j0+tx;
  #pragma unroll
  for(int ol=0;ol<2;ol++)
    xm[((size_t)(b*6+2*g+ol)*H2 + ii)*H2 + jj]=tanhf_(acc[ol]);
}

// ---------------- final ----------------
__global__ __launch_bounds__(256) void k_final(const float* xm, const float* CH, const float* w1,
      const float* w2, const float* sc, const float* bi, const float* dfl, void* outp){
  int isbf = dfl[0]>0.5f;
  int p=blockIdx.x*256+threadIdx.x;
  int b=p>>14; int rem=p&16383;
  float v[6];
  #pragma unroll
  for(int d=0;d<6;d++) v[d]=xm[((size_t)(b*6+d)*HW2)+rem];
  float born[6]={0.f,0.f,0.f,0.f,0.f,0.f};
  for(int c=0;c<NC;c++){
    float y=0.f;
    #pragma unroll
    for(int d=0;d<6;d++) y+=w1[c*6+d]*v[d];
    float a=tanhf_(sc[c]*y+bi[c]);
    #pragma unroll
    for(int d=0;d<6;d++) born[d]+=w2[d*NC+c]*a;
  }
  float C=CH[p];
  #pragma unroll
  for(int d=0;d<6;d++){
    float o=v[d]*(1.f-C)+C*born[d];
    if(d<3) o=sigm_(o);
    size_t id=((size_t)(b*6+d)*HW2)+rem;
    if(isbf) ((ushort_t*)outp)[id]=f2bf(o); else ((float*)outp)[id]=o;
  }
}

extern "C" void kernel_launch(void* const* d_in, const int* in_sizes, int n_in,
                              void* d_out, int out_size, void* d_ws, size_t ws_size,
                              hipStream_t stream){
  (void)in_sizes; (void)n_in; (void)out_size; (void)ws_size;
  const ushort_t* x    = (const ushort_t*)d_in[0];
  const ushort_t* cew1 = (const ushort_t*)d_in[1];
  const void*     ceg  = d_in[2];
  const void*     ceb  = d_in[3];
  const ushort_t* cew2 = (const ushort_t*)d_in[4];
  const ushort_t* mdct = (const ushort_t*)d_in[5];
  const ushort_t* mdc1 = (const ushort_t*)d_in[6];
  const void*     mdg  = d_in[7];
  const void*     mdb  = d_in[8];
  const ushort_t* mdc2 = (const ushort_t*)d_in[9];
  const ushort_t* cmw1 = (const ushort_t*)d_in[10];
  const void*     cmg  = d_in[11];
  const void*     cmb  = d_in[12];
  const ushort_t* cmct = (const ushort_t*)d_in[13];
  const ushort_t* cmc2 = (const ushort_t*)d_in[14];
  const ushort_t* bow1 = (const ushort_t*)d_in[15];
  const void*     bog  = d_in[16];
  const void*     bob  = d_in[17];
  const ushort_t* bow2 = (const ushort_t*)d_in[18];
  float* ws = (float*)d_ws;

  const long OW_mdct=0, OW_mdc1=4320, OW_cew1=25056, OW_cew2=25344, OW_mdc2=25392,
             OW_cmw1=25584, OW_cmct=25968, OW_cmc2=32880, OW_bow1=33744, OW_bow2=34032;
  const long OFF_STATS=34320;
  const long ST_xmom=OFF_STATS+0,  ST_cesc=OFF_STATS+64,  ST_cebi=OFF_STATS+112,
             ST_h2  =OFF_STATS+160, ST_mdsc=OFF_STATS+256, ST_mdbi=OFF_STATS+304,
             ST_t1  =OFF_STATS+352, ST_cmsc=OFF_STATS+448, ST_cmbi=OFF_STATS+496,
             ST_xmm =OFF_STATS+544, ST_bosc=OFF_STATS+608, ST_bobi=OFF_STATS+656,
             ST_FLAG=OFF_STATS+960;
  const long OFF_WB2 = OFF_STATS + 1024;
  const long OFF_WB1 = OFF_WB2 + 13824;
  const long OFF_E   = OFF_WB1 + 6912;
  const long OFF_H2  = OFF_E + 524288L;        // h2 bf16 planar: 12582912 float-slots
  const long OFF_D   = OFF_H2 + 12582912L;     // h1 channels-last bf16, later t1/t2/xm/CH
  const long OFF_T1=OFF_D, OFF_T2=OFF_D+6291456L, OFF_XM=OFF_D+12781056L, OFF_CH=OFF_D+13567488L;

  ushort_t* h1cl = (ushort_t*)(ws + OFF_D);
  ushort_t* h2h  = (ushort_t*)(ws + OFF_H2);
  ushort_t* wb2  = (ushort_t*)(ws + OFF_WB2);
  ushort_t* wb1  = (ushort_t*)(ws + OFF_WB1);
  const float* dfl = ws + ST_FLAG;

  (void)hipMemsetAsync(ws + OFF_STATS, 0, 1024*sizeof(float), stream);
  hipLaunchKernelGGL(k_detect, dim3(1), 256, 0, stream, x, ws+ST_FLAG);

  WC wc;
  const ushort_t* srcs[10] = {mdct,mdc1,cew1,cew2,mdc2,cmw1,cmct,cmc2,bow1,bow2};
  const int offs[10] = {(int)OW_mdct,(int)OW_mdc1,(int)OW_cew1,(int)OW_cew2,(int)OW_mdc2,
                        (int)OW_cmw1,(int)OW_cmct,(int)OW_cmc2,(int)OW_bow1,(int)OW_bow2};
  const int cnts[10] = {4320,20736,288,48,192,384,6912,864,288,288};
  for(int i=0;i<10;i++){ wc.src[i]=srcs[i]; wc.off[i]=offs[i]; wc.n[i]=cnts[i]; }
  hipLaunchKernelGGL(k_wcvt, dim3(81,10), 256, 0, stream, wc, ws, dfl);
  hipLaunchKernelGGL(k_wprep, dim3(21), 256, 0, stream, ws+OW_mdc1, ws+OW_mdct, wb2, wb1);

  // compenv
  hipLaunchKernelGGL(k_mom, dim3(256), 256, 0, stream, (const void*)x, dfl, 0, 16, B8*HWp, ws+ST_xmom);
  hipLaunchKernelGGL(k_msb, dim3(1), 64, 0, stream, ws+ST_xmom, ws+OW_cew1, ceg, ceb, dfl,
                     1.f/(float)(B8*HWp), ws+ST_cesc, ws+ST_cebi);
  hipLaunchKernelGGL(k_env, dim3(2048), 256, 0, stream, (const void*)x, dfl, ws+OW_cew1, ws+OW_cew2,
                     ws+ST_cesc, ws+ST_cebi, ws+OFF_E);

  // md chain (MFMA, h1 channels-last, fused h2 stats)
  hipLaunchKernelGGL(k_h1m, dim3(289,8), 256, 0, stream, (const void*)x, dfl, ws+OFF_E, wb1, h1cl);
  hipLaunchKernelGGL(k_h2m, dim3(256,8), 256, 0, stream, h1cl, wb2, h2h, ws+ST_h2);
  hipLaunchKernelGGL(k_csb, dim3(1), 64, 0, stream, ws+ST_h2, mdg, mdb, dfl, 1.f/(float)(B8*HWp),
                     ws+ST_mdsc, ws+ST_mdbi);
  hipLaunchKernelGGL(k_change, dim3(512), 256, 0, stream, h2h, ws+OW_mdc2,
                     ws+ST_mdsc, ws+ST_mdbi, ws+OFF_CH);

  // cm chain (h1 region dead; t1/t2/xm/CH overlay it)
  hipLaunchKernelGGL(k_cm1, dim3(512), 256, 0, stream, (const void*)x, dfl, ws+OW_cmw1, ws+OFF_T1);
  hipLaunchKernelGGL(k_cstat, dim3(48*8), 256, 0, stream, ws+OFF_T1, (const ushort_t*)nullptr, 0,
                     NC, HW2, B8, 8, ws+ST_t1);
  hipLaunchKernelGGL(k_csb, dim3(1), 64, 0, stream, ws+ST_t1, cmg, cmb, dfl, 1.f/(float)(B8*HW2),
                     ws+ST_cmsc, ws+ST_cmbi);
  hipLaunchKernelGGL(k_cm2, dim3(81,8,3), 256, 0, stream, ws+OFF_T1, ws+ST_cmsc, ws+ST_cmbi,
                     ws+OW_cmct, ws+OFF_T2);
  hipLaunchKernelGGL(k_cm3, dim3(64,8,3), 256, 0, stream, ws+OFF_T2, ws+OW_cmc2, ws+OFF_XM);

  // born + blend
  hipLaunchKernelGGL(k_mom, dim3(128), 256, 0, stream, (const void*)(ws+OFF_XM), (const float*)nullptr, 0,
                     14, B8*HW2, ws+ST_xmm);
  hipLaunchKernelGGL(k_msb, dim3(1), 64, 0, stream, ws+ST_xmm, ws+OW_bow1, bog, bob, dfl,
                     1.f/(float)(B8*HW2), ws+ST_bosc, ws+ST_bobi);
  hipLaunchKernelGGL(k_final, dim3(512), 256, 0, stream, ws+OFF_XM, ws+OFF_CH, ws+OW_bow1,
                     ws+OW_bow2, ws+ST_bosc, ws+ST_bobi, dfl, d_out);
}